// Round 7
// baseline (2268.271 us; speedup 1.0000x reference)
//
#include <hip/hip_runtime.h>
#include <math.h>

// ---------------------------------------------------------------------------
// MPNCOV / iSQRT-COV, FULLY FUSED: one 1024-thread workgroup per batch image.
//   All chain matrices (256x256, symmetric) live in REGISTERS, distributed as
//   16 waves x (64x64 tile in MFMA C-layout), packed bf16 hi|lo (1 u32/elem).
//   Products are intra-workgroup GEMMs: per 32-k chunk the owning wave-column
//   dumps operand slices (register->LDS, symmetry makes both panels row-form)
//   into two 32KB panels; all waves read frags; 3-term split-bf16 MFMA
//   (AhBh + AhBl + AlBh, fp32 accum, ~2^-17 rel).
//   Global traffic: read X once, write triu(out) once. No intermediates.
//   Liveness (3 matrix slots M0/M1/M2 + fp32 acc):
//     cov -> Z1=1.5I-0.5A in M0          (A = 3I - 2*Z1 is never stored)
//     P1 = Z1@Z1   -> Y1  = 3*Z1 - 2*P1      -> M1
//     P2 = Z1@Y1   -> ZY1 = 1.5I - 0.5*P2    -> M2
//     P3 = Y1@ZY1  -> Y2' = sqrt(n)*P3       -> M1   (Y1 dead)
//     P4 = ZY1@Z1  -> Z2' = (1/sqrt(n))*P4   -> M0   (Z1, ZY1 dead)
//     P5 = Z2'@Y2' -> T   = 1.5I - 0.5*P5    -> M2
//     P6 = Y2'@T   -> out = triu(P6)         (scale folded into Y2')
//   mu / trace(n) computed in-block during X staging (no aux kernels).
// ---------------------------------------------------------------------------

#define BB 256
#define CC 256
#define MN 196
#define TRI 32896

typedef __attribute__((ext_vector_type(8))) short short8;   // 8 bf16
typedef __attribute__((ext_vector_type(4))) float f32x4;
typedef __attribute__((ext_vector_type(4))) unsigned int u32x4;

__device__ __forceinline__ unsigned short f2bf(float x) {   // RNE fp32->bf16
    unsigned u = __float_as_uint(x);
    u += 0x7fffu + ((u >> 16) & 1u);
    return (unsigned short)(u >> 16);
}
__device__ __forceinline__ float bf2f(unsigned short h) {
    return __uint_as_float(((unsigned)h) << 16);
}
__device__ __forceinline__ unsigned packsplit(float x) {    // hi|lo in one u32
    unsigned short h = f2bf(x);
    unsigned short l = f2bf(x - bf2f(h));
    return (((unsigned)h) << 16) | (unsigned)l;
}
__device__ __forceinline__ float unpackf(unsigned w) {
    return __uint_as_float(w & 0xffff0000u) + __uint_as_float(w << 16);
}

// read one A/B fragment (16 rows x 32 k, this lane's 8 k-words) from a panel
// row stride 32 words, R6-proven XOR quad swizzle: quad' = (kk>>2) ^ (row&7)
__device__ __forceinline__ void fragone(const unsigned* __restrict__ P, int r,
                                        int q, short8& fh, short8& fl) {
    const unsigned* rp = P + r * 32;
    const int r7 = r & 7;
    u32x4 wa = *(const u32x4*)(rp + (((2 * q)     ^ r7) << 2));
    u32x4 wb = *(const u32x4*)(rp + (((2 * q + 1) ^ r7) << 2));
    #pragma unroll
    for (int j = 0; j < 4; ++j) {
        fh[j]     = (short)(wa[j] >> 16); fl[j]     = (short)(wa[j] & 0xffffu);
        fh[j + 4] = (short)(wb[j] >> 16); fl[j + 4] = (short)(wb[j] & 0xffffu);
    }
}

// one 32-k chunk of MFMA for this wave's 64x64 tile (A rows from pa, B from pbr)
__device__ __forceinline__ void chunk_mfma(const unsigned* __restrict__ pa,
                                           const unsigned* __restrict__ pbr,
                                           f32x4 (&acc)[4][4],
                                           int wr, int wc, int q, int m15) {
    short8 fah[4], fal[4];
    #pragma unroll
    for (int f = 0; f < 4; ++f)
        fragone(pa, wr * 64 + f * 16 + m15, q, fah[f], fal[f]);
    #pragma unroll
    for (int ni = 0; ni < 4; ++ni) {
        short8 bh, bl;
        fragone(pbr, wc * 64 + ni * 16 + m15, q, bh, bl);
        #pragma unroll
        for (int mi = 0; mi < 4; ++mi) {
            acc[mi][ni] = __builtin_amdgcn_mfma_f32_16x16x32_bf16(fal[mi], bh, acc[mi][ni], 0, 0, 0);
            acc[mi][ni] = __builtin_amdgcn_mfma_f32_16x16x32_bf16(fah[mi], bl, acc[mi][ni], 0, 0, 0);
            acc[mi][ni] = __builtin_amdgcn_mfma_f32_16x16x32_bf16(fah[mi], bh, acc[mi][ni], 0, 0, 0);
        }
    }
}

// dump this wave's register slice (cols [NB*16, NB*16+32) local) into panels.
// constant NB keeps all register-array indices static (no scratch spill).
#define DUMP_SLICE(NB)                                                        \
    {                                                                         \
        _Pragma("unroll")                                                     \
        for (int mi = 0; mi < 4; ++mi) {                                      \
            _Pragma("unroll")                                                 \
            for (int h = 0; h < 2; ++h) {                                     \
                _Pragma("unroll")                                             \
                for (int r = 0; r < 4; ++r) {                                 \
                    const int row = wr * 64 + mi * 16 + q * 4 + r;            \
                    const int kk  = h * 16 + m15;                             \
                    const int ad  = row * 32 + (((kk >> 2) ^ (row & 7)) << 2) \
                                    + (kk & 3);                               \
                    pa[ad] = U[mi][(NB) + h][r];                              \
                    if (!SAME) pb[ad] = V[mi][(NB) + h][r];                   \
                }                                                             \
            }                                                                 \
        }                                                                     \
    }

// acc = U @ V  (both 256x256 symmetric, distributed packed in registers)
template <bool SAME>
__device__ __forceinline__ void product(const unsigned (&U)[4][4][4],
                                        const unsigned (&V)[4][4][4],
                                        f32x4 (&acc)[4][4],
                                        unsigned* pa, unsigned* pb,
                                        int wr, int wc, int q, int m15) {
    #pragma unroll
    for (int mi = 0; mi < 4; ++mi)
        #pragma unroll
        for (int ni = 0; ni < 4; ++ni) acc[mi][ni] = (f32x4){0.f, 0.f, 0.f, 0.f};
    #pragma unroll 1
    for (int kc = 0; kc < 8; ++kc) {
        __syncthreads();                       // WAR vs previous chunk reads
        if (wc == (kc >> 1)) {                 // owning wave-column dumps
            if (kc & 1) DUMP_SLICE(2) else DUMP_SLICE(0)
        }
        __syncthreads();                       // RAW: panels ready
        const unsigned* pbr;
        if (SAME) pbr = pa; else pbr = pb;
        chunk_mfma(pa, pbr, acc, wr, wc, q, m15);
    }
}

// ---------------------------------------------------------------------------
__global__ __launch_bounds__(1024) void fused_kernel(const float* __restrict__ x,
                                                     float* __restrict__ out) {
    __shared__ __align__(16) unsigned pa[256 * 32];   // 32 KB panel A
    __shared__ __align__(16) unsigned pb[256 * 32];   // 32 KB panel B / scratch
    const int b = blockIdx.x;
    const int tid = threadIdx.x;
    const int w = tid >> 6, lane = tid & 63;
    const int wr = w >> 2, wc = w & 3;                // 4x4 wave grid, 64x64 tiles
    const int q = lane >> 4, m15 = lane & 15;

    unsigned M0[4][4][4], M1[4][4][4], M2[4][4][4];   // packed matrix tiles
    f32x4 acc[4][4];

    // ---------------- cov: G = Xp @ Xp^T  (K = 224, 7 chunks) --------------
    #pragma unroll
    for (int mi = 0; mi < 4; ++mi)
        #pragma unroll
        for (int ni = 0; ni < 4; ++ni) acc[mi][ni] = (f32x4){0.f, 0.f, 0.f, 0.f};

    float psum = 0.f, psq = 0.f;                      // mu/trace partials
    const int srow = tid >> 2;                        // staging: 4 threads/row
    const int k8   = (tid & 3) * 8;                   // 8 floats each
    const float* xrow = x + ((size_t)b * CC + srow) * MN;

    #pragma unroll 1
    for (int kc = 0; kc < 7; ++kc) {
        const int K0 = kc * 32;
        __syncthreads();                              // WAR vs previous reads
        #pragma unroll
        for (int c = 0; c < 2; ++c) {
            u32x4 pk;
            #pragma unroll
            for (int j = 0; j < 4; ++j) {
                const int k = K0 + k8 + c * 4 + j;
                float xv = 0.f;
                if (k < MN) xv = xrow[k];
                psum += xv; psq += xv * xv;
                pk[j] = packsplit(xv);
            }
            const int kq = (k8 >> 2) + c;
            *(u32x4*)&pa[srow * 32 + ((kq ^ (srow & 7)) << 2)] = pk;
        }
        __syncthreads();
        chunk_mfma(pa, pa, acc, wr, wc, q, m15);      // X@X^T: one panel
    }

    // ---- in-block mu + trace reduction (pb is free during cov) ----
    float* red = (float*)pb;
    __syncthreads();
    red[tid] = psum; red[1024 + tid] = psq;
    __syncthreads();
    if (tid < 256) {
        float s  = red[4*tid] + red[4*tid+1] + red[4*tid+2] + red[4*tid+3];
        float sq = red[1024+4*tid] + red[1024+4*tid+1] + red[1024+4*tid+2] + red[1024+4*tid+3];
        float m = s * (1.0f / MN);
        red[2048 + tid] = m;                          // mu
        red[2304 + tid] = sq * (1.0f / MN) - m * m;   // diag(cov) contrib
    }
    __syncthreads();
    for (int s = 128; s > 0; s >>= 1) {
        if (tid < s) red[2304 + tid] += red[2304 + tid + s];
        __syncthreads();
    }
    const float n   = red[2304];                      // trace = normA
    const float ivv = 1.0f / n;
    const float sn  = sqrtf(n);
    const float ivs = 1.0f / sn;
    const float ivm = ivv * (1.0f / MN);

    // ---- cov epilogue: Z1 = 1.5I - 0.5*A, A = (G/M - mu mu^T)/n -> M0 ----
    {
        float mur[4][4], muc[4];
        #pragma unroll
        for (int mi = 0; mi < 4; ++mi)
            #pragma unroll
            for (int r = 0; r < 4; ++r)
                mur[mi][r] = red[2048 + wr * 64 + mi * 16 + q * 4 + r] * ivv;
        #pragma unroll
        for (int ni = 0; ni < 4; ++ni)
            muc[ni] = red[2048 + wc * 64 + ni * 16 + m15];
        #pragma unroll
        for (int mi = 0; mi < 4; ++mi)
            #pragma unroll
            for (int ni = 0; ni < 4; ++ni)
                #pragma unroll
                for (int r = 0; r < 4; ++r) {
                    const int gr = wr * 64 + mi * 16 + q * 4 + r;
                    const int gc = wc * 64 + ni * 16 + m15;
                    float a = acc[mi][ni][r] * ivm - mur[mi][r] * muc[ni];
                    float z = ((gr == gc) ? 1.5f : 0.0f) - 0.5f * a;
                    M0[mi][ni][r] = packsplit(z);
                }
    }
    // NOTE: mu data in pb stays valid through P1 (SAME=true never writes pb).

    // ---- P1: Y1 = 3*Z1 - 2*(Z1@Z1) -> M1 ----
    product<true>(M0, M0, acc, pa, pb, wr, wc, q, m15);
    #pragma unroll
    for (int mi = 0; mi < 4; ++mi)
        #pragma unroll
        for (int ni = 0; ni < 4; ++ni)
            #pragma unroll
            for (int r = 0; r < 4; ++r)
                M1[mi][ni][r] = packsplit(3.0f * unpackf(M0[mi][ni][r]) - 2.0f * acc[mi][ni][r]);

    // ---- P2: ZY1 = 1.5I - 0.5*(Z1@Y1) -> M2 ----
    product<false>(M0, M1, acc, pa, pb, wr, wc, q, m15);
    #pragma unroll
    for (int mi = 0; mi < 4; ++mi)
        #pragma unroll
        for (int ni = 0; ni < 4; ++ni)
            #pragma unroll
            for (int r = 0; r < 4; ++r) {
                const int gr = wr * 64 + mi * 16 + q * 4 + r;
                const int gc = wc * 64 + ni * 16 + m15;
                float v = ((gr == gc) ? 1.5f : 0.0f) - 0.5f * acc[mi][ni][r];
                M2[mi][ni][r] = packsplit(v);
            }

    // ---- P3: Y2' = sqrt(n)*(Y1@ZY1) -> M1 ----
    product<false>(M1, M2, acc, pa, pb, wr, wc, q, m15);
    #pragma unroll
    for (int mi = 0; mi < 4; ++mi)
        #pragma unroll
        for (int ni = 0; ni < 4; ++ni)
            #pragma unroll
            for (int r = 0; r < 4; ++r)
                M1[mi][ni][r] = packsplit(sn * acc[mi][ni][r]);

    // ---- P4: Z2' = (1/sqrt(n))*(ZY1@Z1) -> M0 ----
    product<false>(M2, M0, acc, pa, pb, wr, wc, q, m15);
    #pragma unroll
    for (int mi = 0; mi < 4; ++mi)
        #pragma unroll
        for (int ni = 0; ni < 4; ++ni)
            #pragma unroll
            for (int r = 0; r < 4; ++r)
                M0[mi][ni][r] = packsplit(ivs * acc[mi][ni][r]);

    // ---- P5: T = 1.5I - 0.5*(Z2'@Y2') -> M2 ----
    product<false>(M0, M1, acc, pa, pb, wr, wc, q, m15);
    #pragma unroll
    for (int mi = 0; mi < 4; ++mi)
        #pragma unroll
        for (int ni = 0; ni < 4; ++ni)
            #pragma unroll
            for (int r = 0; r < 4; ++r) {
                const int gr = wr * 64 + mi * 16 + q * 4 + r;
                const int gc = wc * 64 + ni * 16 + m15;
                float v = ((gr == gc) ? 1.5f : 0.0f) - 0.5f * acc[mi][ni][r];
                M2[mi][ni][r] = packsplit(v);
            }

    // ---- P6: out = triu(Y2'@T) ----
    product<false>(M1, M2, acc, pa, pb, wr, wc, q, m15);
    if (wc >= wr) {
        float* ob = out + (size_t)b * TRI;
        #pragma unroll
        for (int mi = 0; mi < 4; ++mi)
            #pragma unroll
            for (int r = 0; r < 4; ++r) {
                const int gr = wr * 64 + mi * 16 + q * 4 + r;
                const int rowbase = gr * CC - (gr * (gr - 1)) / 2 - gr;
                #pragma unroll
                for (int ni = 0; ni < 4; ++ni) {
                    const int gc = wc * 64 + ni * 16 + m15;
                    if (wc > wr || gc >= gr)
                        ob[rowbase + gc] = acc[mi][ni][r];
                }
            }
    }
}

// ---------------------------------------------------------------------------
extern "C" void kernel_launch(void* const* d_in, const int* in_sizes, int n_in,
                              void* d_out, int out_size, void* d_ws, size_t ws_size,
                              hipStream_t stream) {
    const float* x = (const float*)d_in[0];
    float* out = (float*)d_out;
    (void)d_ws; (void)ws_size;                 // workspace unused: all resident
    fused_kernel<<<BB, 1024, 0, stream>>>(x, out);
}